// Round 2
// baseline (295.293 us; speedup 1.0000x reference)
//
#include <hip/hip_runtime.h>

typedef _Float16 half8  __attribute__((ext_vector_type(8)));
typedef float    floatx4 __attribute__((ext_vector_type(4)));

#define N_NODES 50000
#define N_EDGES 800000
#define SLOPE 0.05f

// ---- workspace layout (bytes) ----
// z:   fp16 [N_NODES][128]   = x @ W0 (no bias, no activation)
// Wt1: fp16 [128][128]       Wt1[n][k] = W1[k][n]
// Wt2: fp16 [64][128]        Wt2[n][k] = W2[k][n]
// b0,b1,b2: fp32
#define WS_Z   0ull
#define WS_W1  (WS_Z  + (size_t)N_NODES * 128 * 2)
#define WS_W2  (WS_W1 + 128 * 128 * 2)
#define WS_B0  (WS_W2 + 64 * 128 * 2)
#define WS_B1  (WS_B0 + 128 * 4)
#define WS_B2  (WS_B1 + 128 * 4)

#define W0_STRIDE 72    // 64 + 8 fp16 pad: keeps 16B row alignment, 2-way-free banks
#define H_STRIDE 136    // 128 + 8 fp16 pad
#define HC_STRIDE 40    // 32 + 8 fp16 pad

__device__ __forceinline__ float leaky(float t) { return t >= 0.f ? t : SLOPE * t; }

// ---------------- kernel 1: weight transpose + fp16 convert ----------------
__global__ void wprep_kernel(const float* __restrict__ W1, const float* __restrict__ W2,
                             const float* __restrict__ b0, const float* __restrict__ b1,
                             const float* __restrict__ b2, unsigned char* __restrict__ ws) {
    _Float16* wt1 = (_Float16*)(ws + WS_W1);
    _Float16* wt2 = (_Float16*)(ws + WS_W2);
    float* B0 = (float*)(ws + WS_B0);
    float* B1 = (float*)(ws + WS_B1);
    float* B2 = (float*)(ws + WS_B2);
    int t = blockIdx.x * 1024 + threadIdx.x;
    if (t < 16384) {                       // W1 [128][128] -> Wt1[n][k]
        int k = t >> 7, n = t & 127;
        wt1[n * 128 + k] = (_Float16)W1[k * 128 + n];
    } else if (t < 24576) {                // W2 [128][64] -> Wt2[n][k]
        int i = t - 16384;
        int k = i >> 6, n = i & 63;
        wt2[n * 128 + k] = (_Float16)W2[k * 64 + n];
    } else if (t < 24576 + 320) {
        int i = t - 24576;
        if (i < 128) B0[i] = b0[i];
        else if (i < 256) B1[i - 128] = b1[i - 128];
        else B2[i - 256] = b2[i - 256];
    }
}

// ---------------- kernel 2: z = x @ W0  (fp16 out) ----------------
__global__ __launch_bounds__(512, 4) void z_kernel(const float* __restrict__ x,
                                                   const float* __restrict__ W0,
                                                   unsigned char* __restrict__ ws) {
    __shared__ __align__(16) _Float16 w0t[128 * W0_STRIDE];
    __shared__ __align__(16) _Float16 hbuf[8][16 * H_STRIDE];
    _Float16* __restrict__ z = (_Float16*)(ws + WS_Z);

    {   // stage W0^T into LDS as fp16: w0t[n][k]
        int t = threadIdx.x;
        int n = t >> 2, k0 = (t & 3) * 16;
        half8 t0, t1;
        #pragma unroll
        for (int j = 0; j < 8; ++j) t0[j] = (_Float16)W0[(k0 + j) * 128 + n];
        #pragma unroll
        for (int j = 0; j < 8; ++j) t1[j] = (_Float16)W0[(k0 + 8 + j) * 128 + n];
        *(half8*)&w0t[n * W0_STRIDE + k0] = t0;
        *(half8*)&w0t[n * W0_STRIDE + k0 + 8] = t1;
    }
    __syncthreads();

    const int wave = threadIdx.x >> 6, lane = threadIdx.x & 63;
    const int cl = lane & 15, q = lane >> 4;
    const int rowbase = blockIdx.x * 128 + wave * 16;
    int row = rowbase + cl; if (row > N_NODES - 1) row = N_NODES - 1;

    // A-frags straight from x rows: A[m=lane&15][k=quad*8+j]
    half8 a[2];
    #pragma unroll
    for (int ks = 0; ks < 2; ++ks) {
        const floatx4* px = (const floatx4*)(x + (size_t)row * 64 + ks * 32 + q * 8);
        floatx4 u0 = px[0], u1 = px[1];
        #pragma unroll
        for (int j = 0; j < 4; ++j) { a[ks][j] = (_Float16)u0[j]; a[ks][4 + j] = (_Float16)u1[j]; }
    }

    _Float16* hs = &hbuf[wave][0];
    #pragma unroll
    for (int n = 0; n < 8; ++n) {
        floatx4 c = {0.f, 0.f, 0.f, 0.f};
        #pragma unroll
        for (int ks = 0; ks < 2; ++ks) {
            half8 b = *(const half8*)&w0t[(n * 16 + cl) * W0_STRIDE + ks * 32 + q * 8];
            c = __builtin_amdgcn_mfma_f32_16x16x32_f16(a[ks], b, c, 0, 0, 0);
        }
        #pragma unroll
        for (int r = 0; r < 4; ++r)   // C/D: col=lane&15, row=quad*4+reg
            hs[(q * 4 + r) * H_STRIDE + n * 16 + cl] = (_Float16)c[r];
    }

    // coalesced LDS slice -> global z
    int rl = lane >> 2, ch = lane & 3;
    int grow = rowbase + rl;
    if (grow < N_NODES) {
        #pragma unroll
        for (int i = 0; i < 4; ++i)
            *(half8*)(z + (size_t)grow * 128 + i * 32 + ch * 8) =
                *(const half8*)&hs[rl * H_STRIDE + i * 32 + ch * 8];
    }
}

// ---------------- kernel 3: per-edge fused MLP (layers 1,2) ----------------
__global__ __launch_bounds__(512, 4) void edge_kernel(const int* __restrict__ ei,
                                                      const unsigned char* __restrict__ ws,
                                                      float* __restrict__ out) {
    __shared__ __align__(16) _Float16 w1s[128 * H_STRIDE];   // 34816 B
    __shared__ __align__(16) _Float16 w2s[64 * H_STRIDE];    // 17408 B
    __shared__ __align__(16) _Float16 hc[8][16 * HC_STRIDE]; // 10240 B
    __shared__ float b0s[128], b1s[128], b2s[64];            // total 63.7 KB

    const _Float16* __restrict__ z    = (const _Float16*)(ws + WS_Z);
    const _Float16* __restrict__ wt1g = (const _Float16*)(ws + WS_W1);
    const _Float16* __restrict__ wt2g = (const _Float16*)(ws + WS_W2);

    {   // stage weights into LDS with padded stride
        int t = threadIdx.x;
        #pragma unroll
        for (int it = 0; it < 4; ++it) {
            int c = t + it * 512;               // 2048 chunks of 8 fp16
            int row = c >> 4, cc = c & 15;
            *(half8*)&w1s[row * H_STRIDE + cc * 8] = *(const half8*)&wt1g[row * 128 + cc * 8];
        }
        #pragma unroll
        for (int it = 0; it < 2; ++it) {
            int c = t + it * 512;               // 1024 chunks
            int row = c >> 4, cc = c & 15;
            *(half8*)&w2s[row * H_STRIDE + cc * 8] = *(const half8*)&wt2g[row * 128 + cc * 8];
        }
        if (t < 128) {
            b0s[t] = *(const float*)(ws + WS_B0 + t * 4);
            b1s[t] = *(const float*)(ws + WS_B1 + t * 4);
        } else if (t < 192) {
            b2s[t - 128] = *(const float*)(ws + WS_B2 + (size_t)(t - 128) * 4);
        }
    }
    __syncthreads();

    const int wave = threadIdx.x >> 6, lane = threadIdx.x & 63;
    const int cl = lane & 15, q = lane >> 4;
    const int rowbase = blockIdx.x * 128 + wave * 16;

    // gather: h0 = leaky(z[s] + z[d] + b0), built directly as A-frags in regs
    // NOTE: harness delivers integer inputs as int32 — ei is int32, row-major [2][E]
    const int r = rowbase + cl;
    const int s = ei[r];
    const int d = ei[N_EDGES + r];
    const _Float16* zs = z + (size_t)s * 128;
    const _Float16* zd = z + (size_t)d * 128;

    half8 a1[4];
    #pragma unroll
    for (int ks = 0; ks < 4; ++ks) {
        half8 u = *(const half8*)(zs + ks * 32 + q * 8);
        half8 v = *(const half8*)(zd + ks * 32 + q * 8);
        floatx4 bA = *(const floatx4*)&b0s[ks * 32 + q * 8];
        floatx4 bB = *(const floatx4*)&b0s[ks * 32 + q * 8 + 4];
        #pragma unroll
        for (int j = 0; j < 4; ++j) {
            float t0 = (float)u[j]     + (float)v[j]     + bA[j];
            float t1 = (float)u[4 + j] + (float)v[4 + j] + bB[j];
            a1[ks][j]     = (_Float16)leaky(t0);
            a1[ks][4 + j] = (_Float16)leaky(t1);
        }
    }

    _Float16* hw = &hc[wave][0];
    floatx4 acc2[4];
    #pragma unroll
    for (int n2 = 0; n2 < 4; ++n2) acc2[n2] = (floatx4){0.f, 0.f, 0.f, 0.f};

    // layer 1 produces h in 32-col chunks (k-step of layer 2), layer 2 consumes them
    #pragma unroll
    for (int ks = 0; ks < 4; ++ks) {
        #pragma unroll
        for (int nn = 0; nn < 2; ++nn) {
            const int n = ks * 2 + nn;
            floatx4 c = {0.f, 0.f, 0.f, 0.f};
            #pragma unroll
            for (int kk = 0; kk < 4; ++kk) {
                half8 b = *(const half8*)&w1s[(n * 16 + cl) * H_STRIDE + kk * 32 + q * 8];
                c = __builtin_amdgcn_mfma_f32_16x16x32_f16(a1[kk], b, c, 0, 0, 0);
            }
            const float bb = b1s[n * 16 + cl];
            #pragma unroll
            for (int rr = 0; rr < 4; ++rr)
                hw[(q * 4 + rr) * HC_STRIDE + nn * 16 + cl] = (_Float16)leaky(c[rr] + bb);
        }
        // C-layout -> A-layout round trip through the per-wave LDS chunk
        half8 a2 = *(const half8*)&hw[cl * HC_STRIDE + q * 8];
        #pragma unroll
        for (int n2 = 0; n2 < 4; ++n2) {
            half8 b = *(const half8*)&w2s[(n2 * 16 + cl) * H_STRIDE + ks * 32 + q * 8];
            acc2[n2] = __builtin_amdgcn_mfma_f32_16x16x32_f16(a2, b, acc2[n2], 0, 0, 0);
        }
    }

    #pragma unroll
    for (int n2 = 0; n2 < 4; ++n2) {
        const float bb = b2s[n2 * 16 + cl];
        #pragma unroll
        for (int rr = 0; rr < 4; ++rr)
            out[(size_t)(rowbase + q * 4 + rr) * 64 + n2 * 16 + cl] = leaky(acc2[n2][rr] + bb);
    }
}

extern "C" void kernel_launch(void* const* d_in, const int* in_sizes, int n_in,
                              void* d_out, int out_size, void* d_ws, size_t ws_size,
                              hipStream_t stream) {
    const float* x  = (const float*)d_in[0];
    const int*   ei = (const int*)d_in[1];     // int inputs arrive as int32
    const float* W0 = (const float*)d_in[2];
    const float* b0 = (const float*)d_in[3];
    const float* W1 = (const float*)d_in[4];
    const float* b1 = (const float*)d_in[5];
    const float* W2 = (const float*)d_in[6];
    const float* b2 = (const float*)d_in[7];
    float* out = (float*)d_out;
    unsigned char* ws = (unsigned char*)d_ws;

    wprep_kernel<<<25, 1024, 0, stream>>>(W1, W2, b0, b1, b2, ws);
    z_kernel<<<(N_NODES + 127) / 128, 512, 0, stream>>>(x, W0, ws);
    edge_kernel<<<N_EDGES / 128, 512, 0, stream>>>(ei, ws, out);
}